// Round 2
// 639.112 us; speedup vs baseline: 1.0154x; 1.0154x over previous
//
#include <hip/hip_runtime.h>

namespace {

constexpr int kT = 51;      // input timesteps
constexpr int kOut = 20;    // decoder steps
constexpr float kL2E  = 1.4426950408889634f;   // log2(e)
constexpr float kL2E2 = 2.8853900817779268f;   // 2*log2(e)

typedef __attribute__((ext_vector_type(8))) short bf16x8;
typedef __attribute__((ext_vector_type(4))) float f32x4;
typedef __attribute__((ext_vector_type(2))) float f32x2;

union FragU {
    bf16x8 v;
    unsigned long long u64[2];
    unsigned int u32[4];
    unsigned short s[8];
};

__device__ __forceinline__ unsigned short f2bf(float x) {
    union { float f; unsigned int u; } v;
    v.f = x;
    unsigned int r = (v.u + 0x7fffu + ((v.u >> 16) & 1u)) >> 16;
    return (unsigned short)r;
}

// pack two floats to bf16x2 (low=bf(a), high=bf(b)): 2x v_add_u32 + v_perm_b32
__device__ __forceinline__ unsigned int packbf(float a, float b) {
    union { float f; unsigned int u; } ua, ub;
    ua.f = a; ub.f = b;
    return __builtin_amdgcn_perm(ub.u + 0x8000u, ua.u + 0x8000u, 0x07060302u);
}

// GRU enc-dec, 4-way unit split x 4 batch groups. Block = 256 thr = 4 waves,
// handling 64 batch rows (groups g=0..3 of 16). Wave w owns hidden units
// [16w,16w+16) for ALL groups (weight frags shared). h' slices exchanged via
// double-buffered LDS, one __syncthreads per step.
// MFMA 16x16x32 layouts: A lane(q,i)=A[m=i][k=8q+j]; B lane(q,i)=B[k=8q+j][n=i];
// C lane(q,i)=C[row=4q+r][col=i]. Weights pre-scaled by log2e (r,z) / 2log2e
// (n) so activations use raw v_exp_f32. Activations run as f32x2 over the
// (even,odd) group pair -> v_pk_*_f32; rcp product-sharing pairs the two
// groups' units: 4 trans/unit (3 exp2 + 1 rcp).
__global__ __launch_bounds__(256, 2) void gru_encdec(
    const float* __restrict__ input,
    const float* __restrict__ eWih, const float* __restrict__ eWhh,
    const float* __restrict__ ebih, const float* __restrict__ ebhh,
    const float* __restrict__ dWih, const float* __restrict__ dWhh,
    const float* __restrict__ dbih, const float* __restrict__ dbhh,
    const float* __restrict__ linW, const float* __restrict__ linb,
    float* __restrict__ out)
{
    // h exchange: [dbuf][group][16 rows x 64 units, stride 68 bf16]
    __shared__ __align__(16) unsigned short hbuf[2][4][16 * 68];

    const int lane = (int)(threadIdx.x & 63u);
    const int w = (int)(threadIdx.x >> 6u);   // unit-quarter owner
    const int q = lane >> 4;
    const int i = lane & 15;
    const bool q0 = (q == 0);
    const long bb = (long)blockIdx.x * 64 + i;   // batch row for group 0

    const float* xrow[4];
#pragma unroll
    for (int g = 0; g < 4; ++g) xrow[g] = input + (bb + 16 * g) * (kT * 4);

    // Per-wave weight fragments: l = 0 (r), 1 (z), 2 (n); tau = 4*l + w
    bf16x8 WA[3][2];     // Whh frags, [l][K-half]
    bf16x8 WAUG[3];      // [Wih(4) | bias | 0...] frags (q0 lanes meaningful)
    f32x4 bhhn4;         // bhh_n * 2l2e as C-init
    float hp[4][4];      // fp32 h per group, [g][r] = h[b][u=16w+4q+r]
    bf16x8 bh[4][2];     // h B-frags per group / K-half
    float px[4][4];
    const f32x4 z4 = {0.f, 0.f, 0.f, 0.f};
    const bf16x8 zfr = {0, 0, 0, 0, 0, 0, 0, 0};

    auto load_whh = [&](const float* __restrict__ Whh) {
#pragma unroll
        for (int l = 0; l < 3; ++l) {
            const int tau = 4 * l + w;
            const float sc = (l < 2) ? kL2E : kL2E2;
#pragma unroll
            for (int f = 0; f < 2; ++f) {
                const float* ptr = Whh + (tau * 16 + i) * 64 + f * 32 + q * 8;
                FragU fu;
#pragma unroll
                for (int j = 0; j < 8; ++j) fu.s[j] = f2bf(ptr[j] * sc);
                WA[l][f] = fu.v;
            }
        }
    };

    auto load_aug = [&](const float* __restrict__ Wih,
                        const float* __restrict__ bih,
                        const float* __restrict__ bhh) {
#pragma unroll
        for (int l = 0; l < 3; ++l) {
            const int tau = 4 * l + w;
            const float sc = (l < 2) ? kL2E : kL2E2;
            FragU fu;
            fu.u64[0] = 0; fu.u64[1] = 0;
            if (q0) {
                int j = tau * 16 + i;
#pragma unroll
                for (int d = 0; d < 4; ++d) fu.s[d] = f2bf(Wih[j * 4 + d] * sc);
                float bias = (l < 2) ? (bih[j] + bhh[j]) : bih[j];
                fu.s[4] = f2bf(bias * sc);
            }
            WAUG[l] = fu.v;
        }
#pragma unroll
        for (int r = 0; r < 4; ++r)
            bhhn4[r] = bhh[128 + 16 * w + 4 * q + r] * kL2E2;
    };

    // B-frag from px: only k<5 rows hit nonzero A columns, so no lane masking
    // needed (q>0 lanes / s[5..7] hit zero A columns).
    auto make_baug = [&](const float* pxv) -> bf16x8 {
        FragU fu;
        fu.u32[0] = packbf(pxv[0], pxv[1]);
        fu.u32[1] = packbf(pxv[2], pxv[3]);
        fu.u32[2] = 0x3f80u;  // bf16(1.0) -> bias column
        fu.u32[3] = 0u;
        return fu.v;
    };

    // One GRU step for all 4 groups; ssel = LDS dbuf (0/1). Groups processed
    // as 2 pairs to bound accumulator liveness; activations in f32x2 pairs.
    auto gru_step = [&](int ssel, const bf16x8* ba) {
#pragma unroll
        for (int p = 0; p < 2; ++p) {
            const int g0 = 2 * p, g1 = 2 * p + 1;
            f32x4 R[2], Z[2], Ni[2], Nh[2];
#pragma unroll
            for (int k = 0; k < 2; ++k) {
                const int g = 2 * p + k;
                R[k] = __builtin_amdgcn_mfma_f32_16x16x32_bf16(WAUG[0], ba[g], z4, 0, 0, 0);
                R[k] = __builtin_amdgcn_mfma_f32_16x16x32_bf16(WA[0][0], bh[g][0], R[k], 0, 0, 0);
                R[k] = __builtin_amdgcn_mfma_f32_16x16x32_bf16(WA[0][1], bh[g][1], R[k], 0, 0, 0);
                Z[k] = __builtin_amdgcn_mfma_f32_16x16x32_bf16(WAUG[1], ba[g], z4, 0, 0, 0);
                Z[k] = __builtin_amdgcn_mfma_f32_16x16x32_bf16(WA[1][0], bh[g][0], Z[k], 0, 0, 0);
                Z[k] = __builtin_amdgcn_mfma_f32_16x16x32_bf16(WA[1][1], bh[g][1], Z[k], 0, 0, 0);
                Ni[k] = __builtin_amdgcn_mfma_f32_16x16x32_bf16(WAUG[2], ba[g], z4, 0, 0, 0);
                Nh[k] = __builtin_amdgcn_mfma_f32_16x16x32_bf16(WA[2][0], bh[g][0], bhhn4, 0, 0, 0);
                Nh[k] = __builtin_amdgcn_mfma_f32_16x16x32_bf16(WA[2][1], bh[g][1], Nh[k], 0, 0, 0);
            }
            float hva[4], hvb[4];
            const f32x2 one = {1.f, 1.f};
            const f32x2 m2 = {-2.f, -2.f};
#pragma unroll
            for (int r = 0; r < 4; ++r) {
                f32x2 a = { __builtin_amdgcn_exp2f(-R[0][r]),
                            __builtin_amdgcn_exp2f(-R[1][r]) };
                f32x2 c = { __builtin_amdgcn_exp2f(-Z[0][r]),
                            __builtin_amdgcn_exp2f(-Z[1][r]) };
                f32x2 A = a + one, C = c + one;
                f32x2 P = A * C;
                float rpp = __builtin_amdgcn_rcpf(P.x * P.y);
                f32x2 Ps = {P.y, P.x};
                f32x2 rp = rpp * Ps;              // {1/P.x, 1/P.y}
                f32x2 rr = rp * C;                // sigmoid(xr) pair
                f32x2 zz = rp * A;                // sigmoid(xz) pair
                f32x2 Nh2 = {Nh[0][r], Nh[1][r]};
                f32x2 Ni2 = {Ni[0][r], Ni[1][r]};
                f32x2 p2 = __builtin_elementwise_fma(rr, Nh2, Ni2);
                f32x2 E = { __builtin_amdgcn_exp2f(p2.x),
                            __builtin_amdgcn_exp2f(p2.y) };
                f32x2 D = E + one;
                float rdd = __builtin_amdgcn_rcpf(D.x * D.y);
                f32x2 Ds = {D.y, D.x};
                f32x2 t = rdd * Ds;
                f32x2 n = __builtin_elementwise_fma(t, m2, one);   // tanh
                f32x2 h = {hp[g0][r], hp[g1][r]};
                f32x2 hv = __builtin_elementwise_fma(zz, h - n, n);
                hp[g0][r] = hv.x; hp[g1][r] = hv.y;
                hva[r] = hv.x;    hvb[r] = hv.y;
            }
            uint2 wva, wvb;
            wva.x = packbf(hva[0], hva[1]); wva.y = packbf(hva[2], hva[3]);
            wvb.x = packbf(hvb[0], hvb[1]); wvb.y = packbf(hvb[2], hvb[3]);
            *(uint2*)&hbuf[ssel][g0][i * 68 + 16 * w + 4 * q] = wva;
            *(uint2*)&hbuf[ssel][g1][i * 68 + 16 * w + 4 * q] = wvb;
        }
        __syncthreads();  // h' slices visible block-wide
#pragma unroll
        for (int g = 0; g < 4; ++g) {
            const unsigned short* hw = hbuf[ssel][g];
            FragU fA, fB;
            fA.u64[0] = *(const unsigned long long*)&hw[i * 68 + 8 * q];
            fA.u64[1] = *(const unsigned long long*)&hw[i * 68 + 8 * q + 4];
            fB.u64[0] = *(const unsigned long long*)&hw[i * 68 + 32 + 8 * q];
            fB.u64[1] = *(const unsigned long long*)&hw[i * 68 + 32 + 8 * q + 4];
            bh[g][0] = fA.v;
            bh[g][1] = fB.v;
        }
    };

    // ---------------- encoder ----------------
#pragma unroll
    for (int g = 0; g < 4; ++g) {
#pragma unroll
        for (int r = 0; r < 4; ++r) hp[g][r] = 0.f;
        bh[g][0] = zfr;
        bh[g][1] = zfr;
    }
    load_whh(eWhh);
    load_aug(eWih, ebih, ebhh);

    float4 xp[4], xn[4];
#pragma unroll
    for (int g = 0; g < 4; ++g) {
        xp[g] = *(const float4*)(xrow[g]);
        xn[g] = *(const float4*)(xrow[g] + 4);
    }
    bf16x8 ba[4];
#pragma unroll 2
    for (int s = 0; s < kT - 1; ++s) {
#pragma unroll
        for (int g = 0; g < 4; ++g) {
            px[g][0] = xn[g].x - xp[g].x; px[g][1] = xn[g].y - xp[g].y;
            px[g][2] = xn[g].z - xp[g].z; px[g][3] = xn[g].w - xp[g].w;
            xp[g] = xn[g];
        }
        int idx = s + 2; if (idx > kT - 1) idx = kT - 1;
#pragma unroll
        for (int g = 0; g < 4; ++g)
            xn[g] = *(const float4*)(xrow[g] + idx * 4);   // prefetch next x
#pragma unroll
        for (int g = 0; g < 4; ++g) ba[g] = make_baug(px[g]);
        gru_step(s & 1, ba);
    }
    // after loop: xp[g] = input[b][T-1] (offset); px[g] = diffs[b][T-2]
    float4 off[4];
#pragma unroll
    for (int g = 0; g < 4; ++g) off[g] = xp[g];

    // ---------------- decoder ----------------
    load_whh(dWhh);
    load_aug(dWih, dbih, dbhh);

    // linear head frags (all waves hold them; head computed redundantly so the
    // fp32 px chains stay wave-local and bitwise-identical across waves)
    bf16x8 AL0, AL1, AL2;
    {
        FragU a0, a1, a2;
        a0.u64[0] = a0.u64[1] = 0;
        a1.u64[0] = a1.u64[1] = 0;
        a2.u64[0] = a2.u64[1] = 0;
        if (i < 4) {
            const float* p0 = linW + i * 64 + q * 8;
            const float* p1 = linW + i * 64 + 32 + q * 8;
#pragma unroll
            for (int j = 0; j < 8; ++j) {
                a0.s[j] = f2bf(p0[j]);
                a1.s[j] = f2bf(p1[j]);
            }
            if (q0) a2.s[4] = f2bf(linb[i]);
        }
        AL0 = a0.v; AL1 = a1.v; AL2 = a2.v;
    }

#pragma unroll 2
    for (int s = 0; s < kOut; ++s) {
#pragma unroll
        for (int g = 0; g < 4; ++g) ba[g] = make_baug(px[g]);
        gru_step(s & 1, ba);  // bh frags now hold NEW h
#pragma unroll
        for (int g = 0; g < 4; ++g) {
            f32x4 X = __builtin_amdgcn_mfma_f32_16x16x32_bf16(AL2, ba[g], z4, 0, 0, 0);
            X = __builtin_amdgcn_mfma_f32_16x16x32_bf16(AL0, bh[g][0], X, 0, 0, 0);
            X = __builtin_amdgcn_mfma_f32_16x16x32_bf16(AL1, bh[g][1], X, 0, 0, 0);
            // q0 lanes: X[r] = x_d, d=r, col=i=batch. fp32 px chains.
            px[g][0] += X[0]; px[g][1] += X[1];
            px[g][2] += X[2]; px[g][3] += X[3];
        }
        // direct global store: wave g's q0 lanes own group g's 16 rows.
#pragma unroll
        for (int g = 0; g < 4; ++g) {
            if (w == g && q0) {
                float* op = out + (bb + 16 * g) * (kOut * 4) + s * 4;
                float4 v;
                v.x = px[g][0] + off[g].x; v.y = px[g][1] + off[g].y;
                v.z = px[g][2] + off[g].z; v.w = px[g][3] + off[g].w;
                *(float4*)op = v;
            }
        }
    }
}

}  // namespace

extern "C" void kernel_launch(void* const* d_in, const int* in_sizes, int n_in,
                              void* d_out, int out_size, void* d_ws, size_t ws_size,
                              hipStream_t stream) {
    const float* input = (const float*)d_in[0];
    const float* eWih = (const float*)d_in[1];
    const float* eWhh = (const float*)d_in[2];
    const float* ebih = (const float*)d_in[3];
    const float* ebhh = (const float*)d_in[4];
    const float* dWih = (const float*)d_in[5];
    const float* dWhh = (const float*)d_in[6];
    const float* dbih = (const float*)d_in[7];
    const float* dbhh = (const float*)d_in[8];
    const float* linW = (const float*)d_in[9];
    const float* linb = (const float*)d_in[10];
    float* out = (float*)d_out;

    const int B = in_sizes[0] / (kT * 4);
    const int nblocks = B / 64;   // 64 batch rows per block (4 groups of 16)
    gru_encdec<<<nblocks, 256, 0, stream>>>(input, eWih, eWhh, ebih, ebhh,
                                            dWih, dWhh, dbih, dbhh,
                                            linW, linb, out);
}